// Round 2
// baseline (361.647 us; speedup 1.0000x reference)
//
#include <hip/hip_runtime.h>
#include <hip/hip_bf16.h>
#include <stdint.h>

#define HN     16
#define DMODEL 1024
#define DKH    64
#define SEQL   4096

typedef __attribute__((ext_vector_type(8))) short bf16x8;
typedef __attribute__((ext_vector_type(4))) float f32x4;

typedef const __attribute__((address_space(1))) uint32_t gas_u32;
typedef __attribute__((address_space(3))) uint32_t las_u32;

// async global->LDS, 16B per lane; LDS dest = wave-uniform base + lane*16
__device__ __forceinline__ void gl_lds16(const void* g, void* l) {
  __builtin_amdgcn_global_load_lds((gas_u32*)g, (las_u32*)l, 16, 0, 0);
}

__device__ __forceinline__ unsigned short f2bf(float x) {
  uint32_t u = __float_as_uint(x);
  u = (u + 0x7fffu + ((u >> 16) & 1u)) >> 16;
  return (unsigned short)u;
}

__device__ __forceinline__ uint32_t cvt_pk_bf16(float lo, float hi) {
  uint32_t r;
  asm("v_cvt_pk_bf16_f32 %0, %1, %2" : "=v"(r) : "v"(lo), "v"(hi));
  return r;
}

// ---------------- fp32 -> bf16 conversion (7 tensors fused) ----------------
struct CvtArgs {
  const float *q, *k, *v, *wq, *wk, *wv, *wo;
  unsigned short *qb, *kb, *vb, *wqb, *wkb, *wvb, *wob;
};

__global__ __launch_bounds__(256) void cvt_all(CvtArgs a) {
  const int stride = gridDim.x * blockDim.x;
  for (int v4 = blockIdx.x * blockDim.x + threadIdx.x; v4 < 4194304; v4 += stride) {
    const float* sp; unsigned short* dp; int idx;
    if      (v4 < 1048576) { sp = a.q;  dp = a.qb;  idx = v4; }
    else if (v4 < 2097152) { sp = a.k;  dp = a.kb;  idx = v4 - 1048576; }
    else if (v4 < 3145728) { sp = a.v;  dp = a.vb;  idx = v4 - 2097152; }
    else if (v4 < 3407872) { sp = a.wq; dp = a.wqb; idx = v4 - 3145728; }
    else if (v4 < 3670016) { sp = a.wk; dp = a.wkb; idx = v4 - 3407872; }
    else if (v4 < 3932160) { sp = a.wv; dp = a.wvb; idx = v4 - 3670016; }
    else                   { sp = a.wo; dp = a.wob; idx = v4 - 3932160; }
    float4 f = ((const float4*)sp)[idx];
    ushort4 o;
    o.x = f2bf(f.x); o.y = f2bf(f.y); o.z = f2bf(f.z); o.w = f2bf(f.w);
    ((ushort4*)dp)[idx] = o;
  }
}

// ---------------- GEMM: C = A * W^T + bias  (A:[M,K] bf16, W:[N,K] bf16) ----
// mode 0: bf16 C[M,N]; mode 1: bf16 C^T[N,M]; mode 2: f32 C[M,N]
struct GemmDesc {
  const unsigned short* A;
  const unsigned short* W;
  const float* bias;
  void* C;
  int mode;
};
struct GemmArgs { GemmDesc d[3]; };

__global__ __launch_bounds__(256) void gemm_bt(GemmArgs ga) {
  const GemmDesc gd = ga.d[blockIdx.z];
  constexpr int M = SEQL, N = DMODEL, K = DMODEL;
  __shared__ unsigned short As[128 * 64];
  __shared__ unsigned short Bs[128 * 64];
  const int tid = threadIdx.x;
  const int w = tid >> 6, lane = tid & 63;
  const int g16 = lane >> 4, l16 = lane & 15;
  const int wr = w >> 1, wc = w & 1;
  const int bm0 = blockIdx.y * 128, bn0 = blockIdx.x * 128;
  const int srow = tid >> 3, scc = tid & 7;

  f32x4 acc[4][4];
#pragma unroll
  for (int i = 0; i < 4; ++i)
#pragma unroll
    for (int j = 0; j < 4; ++j)
      acc[i][j] = (f32x4){0.f, 0.f, 0.f, 0.f};

  for (int k0 = 0; k0 < K; k0 += 64) {
    // stage A,B tiles: 16KB each; source pre-swizzled (chunk ^= row&7) so
    // linear LDS + swizzled ds_read is conflict-light (2-way max)
#pragma unroll
    for (int i = 0; i < 4; ++i) {
      int row = i * 32 + srow;
      int sw = scc ^ (row & 7);
      gl_lds16(gd.A + (size_t)(bm0 + row) * K + k0 + sw * 8,
               (void*)(As + (i * 256 + w * 64) * 8));
      gl_lds16(gd.W + (size_t)(bn0 + row) * K + k0 + sw * 8,
               (void*)(Bs + (i * 256 + w * 64) * 8));
    }
    __syncthreads();
#pragma unroll
    for (int ks = 0; ks < 2; ++ks) {
      bf16x8 af[4], bfr[4];
#pragma unroll
      for (int mt = 0; mt < 4; ++mt) {
        int row = wr * 64 + mt * 16 + l16;
        af[mt] = *(const bf16x8*)&As[row * 64 + (((ks * 4 + g16) ^ (row & 7)) * 8)];
      }
#pragma unroll
      for (int nt = 0; nt < 4; ++nt) {
        int row = wc * 64 + nt * 16 + l16;
        bfr[nt] = *(const bf16x8*)&Bs[row * 64 + (((ks * 4 + g16) ^ (row & 7)) * 8)];
      }
#pragma unroll
      for (int mt = 0; mt < 4; ++mt)
#pragma unroll
        for (int nt = 0; nt < 4; ++nt)
          acc[mt][nt] = __builtin_amdgcn_mfma_f32_16x16x32_bf16(af[mt], bfr[nt], acc[mt][nt], 0, 0, 0);
    }
    __syncthreads();
  }

  // epilogue: C/D layout col=lane&15, row=(lane>>4)*4+reg
#pragma unroll
  for (int nt = 0; nt < 4; ++nt) {
    int col = bn0 + wc * 64 + nt * 16 + l16;
    float bcol = gd.bias[col];
#pragma unroll
    for (int mt = 0; mt < 4; ++mt) {
      int row0 = bm0 + wr * 64 + mt * 16 + g16 * 4;
      f32x4 a = acc[mt][nt];
      if (gd.mode == 0) {
        unsigned short* CB = (unsigned short*)gd.C;
#pragma unroll
        for (int r = 0; r < 4; ++r)
          CB[(size_t)(row0 + r) * N + col] = f2bf(a[r] + bcol);
      } else if (gd.mode == 1) {
        unsigned short* CT = (unsigned short*)gd.C;
        ushort4 pk;
        pk.x = f2bf(a[0] + bcol); pk.y = f2bf(a[1] + bcol);
        pk.z = f2bf(a[2] + bcol); pk.w = f2bf(a[3] + bcol);
        *(ushort4*)&CT[(size_t)col * M + row0] = pk;
      } else {
        float* CF = (float*)gd.C;
#pragma unroll
        for (int r = 0; r < 4; ++r)
          CF[(size_t)(row0 + r) * N + col] = a[r] + bcol;
      }
    }
  }
}

// ---------------- flash attention ----------------
// grid (SEQ/64, H); 4 waves/block; wave owns 16 q-rows.
// Swapped QK^T: S^T = K * Q^T, so lane (q=lane&15) holds a full q-row slice.
__global__ __launch_bounds__(256) void attn_fwd(
    const unsigned short* __restrict__ Qm, const unsigned short* __restrict__ Km,
    const unsigned short* __restrict__ Vtm, unsigned short* __restrict__ Xm) {
  __shared__ unsigned short Ksm[64 * 64];
  __shared__ unsigned short Vsm[64 * 64];
  const int tid = threadIdx.x;
  const int w = tid >> 6, lane = tid & 63;
  const int g = lane >> 4, qi = lane & 15;
  const int hb = blockIdx.y * DKH;
  const int q0 = blockIdx.x * 64 + w * 16;
  const int srow = tid >> 3, scc = tid & 7;
  const float CE = 0.18033688011112042f; // log2(e)/sqrt(64)

  // Q as B-operand fragments: lane holds Q[q0+qi][k=(ks*32 + g*8 + j)]
  bf16x8 qf[2];
#pragma unroll
  for (int ks = 0; ks < 2; ++ks)
    qf[ks] = *(const bf16x8*)&Qm[(size_t)(q0 + qi) * DMODEL + hb + ks * 32 + g * 8];

  f32x4 oacc[4];
#pragma unroll
  for (int i = 0; i < 4; ++i) oacc[i] = (f32x4){0.f, 0.f, 0.f, 0.f};
  float mrun = -1e30f, lsum = 0.f;

  for (int t = 0; t < SEQL / 64; ++t) {
    // stage K tile [64kv][64d] and Vt tile [64d][64s], both source-swizzled
#pragma unroll
    for (int i = 0; i < 2; ++i) {
      int row = i * 32 + srow;
      int sw = scc ^ (row & 7);
      gl_lds16(Km + (size_t)(t * 64 + row) * DMODEL + hb + sw * 8,
               (void*)(Ksm + (i * 256 + w * 64) * 8));
      gl_lds16(Vtm + (size_t)(hb + row) * SEQL + t * 64 + sw * 8,
               (void*)(Vsm + (i * 256 + w * 64) * 8));
    }
    __syncthreads();

    // S^T = K * Q^T : 4 kv-tiles of 16
    f32x4 sv[4];
#pragma unroll
    for (int kvt = 0; kvt < 4; ++kvt) sv[kvt] = (f32x4){0.f, 0.f, 0.f, 0.f};
#pragma unroll
    for (int kvt = 0; kvt < 4; ++kvt) {
      int row = kvt * 16 + qi;
      bf16x8 ka0 = *(const bf16x8*)&Ksm[row * 64 + (((0 + g) ^ (row & 7)) * 8)];
      bf16x8 ka1 = *(const bf16x8*)&Ksm[row * 64 + (((4 + g) ^ (row & 7)) * 8)];
      sv[kvt] = __builtin_amdgcn_mfma_f32_16x16x32_bf16(ka0, qf[0], sv[kvt], 0, 0, 0);
      sv[kvt] = __builtin_amdgcn_mfma_f32_16x16x32_bf16(ka1, qf[1], sv[kvt], 0, 0, 0);
    }

    // online softmax: lane owns q=qi; its 16 values are kv = kvt*16 + g*4 + r
    float tmax = sv[0][0];
#pragma unroll
    for (int kvt = 0; kvt < 4; ++kvt)
#pragma unroll
      for (int r = 0; r < 4; ++r) tmax = fmaxf(tmax, sv[kvt][r]);
    tmax = fmaxf(tmax, __shfl_xor(tmax, 16));
    tmax = fmaxf(tmax, __shfl_xor(tmax, 32));
    float mnew = fmaxf(mrun, tmax);
    float alpha = exp2f((mrun - mnew) * CE);

    float p[16];
    float psum = 0.f;
#pragma unroll
    for (int kvt = 0; kvt < 4; ++kvt)
#pragma unroll
      for (int r = 0; r < 4; ++r) {
        float pv = exp2f((sv[kvt][r] - mnew) * CE);
        p[kvt * 4 + r] = pv;
        psum += pv;
      }
    psum += __shfl_xor(psum, 16);
    psum += __shfl_xor(psum, 32);
    lsum = lsum * alpha + psum;
    mrun = mnew;

    // rescale O (O rows live as row=(lane>>4)*4+r): fetch alpha of q=g*4+r
#pragma unroll
    for (int r = 0; r < 4; ++r) {
      float ar = __shfl(alpha, (lane & 48) + g * 4 + r);
#pragma unroll
      for (int dg = 0; dg < 4; ++dg) oacc[dg][r] *= ar;
    }

    // pack P to bf16 pairs: pk2[kvt][w] holds (r=2w, r=2w+1)
    uint32_t pk2[4][2];
#pragma unroll
    for (int kvt = 0; kvt < 4; ++kvt) {
      pk2[kvt][0] = cvt_pk_bf16(p[kvt * 4 + 0], p[kvt * 4 + 1]);
      pk2[kvt][1] = cvt_pk_bf16(p[kvt * 4 + 2], p[kvt * 4 + 3]);
    }

    // transpose P^T lane-layout -> PV A-fragment layout via shfl:
    // frag[ks].word[wp] = pk2[2ks+(g>>1)][wp&1] from lane qi+16*((g&1)*2+(wp>>1))
    union { uint32_t u[4]; bf16x8 v; } pf[2];
#pragma unroll
    for (int ks = 0; ks < 2; ++ks)
#pragma unroll
      for (int wp = 0; wp < 4; ++wp) {
        int src = qi + 16 * ((g & 1) * 2 + (wp >> 1));
        uint32_t v0 = __shfl(pk2[2 * ks][wp & 1], src);
        uint32_t v1 = __shfl(pk2[2 * ks + 1][wp & 1], src);
        pf[ks].u[wp] = (g >> 1) ? v1 : v0;
      }

    // PV: O += P * V  (B-operand from Vt tile rows = d)
#pragma unroll
    for (int dg = 0; dg < 4; ++dg) {
      int row = dg * 16 + qi;
#pragma unroll
      for (int ks = 0; ks < 2; ++ks) {
        bf16x8 vb = *(const bf16x8*)&Vsm[row * 64 + (((ks * 4 + g) ^ (row & 7)) * 8)];
        oacc[dg] = __builtin_amdgcn_mfma_f32_16x16x32_bf16(pf[ks].v, vb, oacc[dg], 0, 0, 0);
      }
    }
    __syncthreads();
  }

  float linv = 1.f / lsum;
#pragma unroll
  for (int r = 0; r < 4; ++r) {
    float lr = __shfl(linv, (lane & 48) + g * 4 + r);
    int row = q0 + g * 4 + r;
#pragma unroll
    for (int dg = 0; dg < 4; ++dg)
      Xm[(size_t)row * DMODEL + hb + dg * 16 + qi] = f2bf(oacc[dg][r] * lr);
  }
}

// ---------------- launch ----------------
extern "C" void kernel_launch(void* const* d_in, const int* in_sizes, int n_in,
                              void* d_out, int out_size, void* d_ws, size_t ws_size,
                              hipStream_t stream) {
  const float* query = (const float*)d_in[0];
  const float* key_  = (const float*)d_in[1];
  const float* value = (const float*)d_in[2];
  const float* Wq = (const float*)d_in[3];
  const float* bq = (const float*)d_in[4];
  const float* Wk = (const float*)d_in[5];
  const float* bk = (const float*)d_in[6];
  const float* Wv = (const float*)d_in[7];
  const float* bv = (const float*)d_in[8];
  const float* Wo = (const float*)d_in[9];
  const float* bo = (const float*)d_in[10];

  char* ws = (char*)d_ws;
  const size_t MB = 1024 * 1024;
  unsigned short* qb  = (unsigned short*)(ws + 0 * MB);
  unsigned short* kb  = (unsigned short*)(ws + 8 * MB);
  unsigned short* vb  = (unsigned short*)(ws + 16 * MB);
  unsigned short* wqb = (unsigned short*)(ws + 24 * MB);
  unsigned short* wkb = (unsigned short*)(ws + 26 * MB);
  unsigned short* wvb = (unsigned short*)(ws + 28 * MB);
  unsigned short* wob = (unsigned short*)(ws + 30 * MB);
  unsigned short* Qp  = (unsigned short*)(ws + 32 * MB);
  unsigned short* Kp  = (unsigned short*)(ws + 40 * MB);
  unsigned short* Vtp = (unsigned short*)(ws + 48 * MB);
  unsigned short* Xp  = (unsigned short*)(ws + 56 * MB);

  CvtArgs ca{query, key_, value, Wq, Wk, Wv, Wo, qb, kb, vb, wqb, wkb, wvb, wob};
  cvt_all<<<dim3(2048), dim3(256), 0, stream>>>(ca);

  GemmArgs gp;
  gp.d[0] = GemmDesc{qb, wqb, bq, (void*)Qp, 0};
  gp.d[1] = GemmDesc{kb, wkb, bk, (void*)Kp, 0};
  gp.d[2] = GemmDesc{vb, wvb, bv, (void*)Vtp, 1}; // V written transposed [d][s]
  gemm_bt<<<dim3(8, 32, 3), dim3(256), 0, stream>>>(gp);

  attn_fwd<<<dim3(SEQL / 64, HN), dim3(256), 0, stream>>>(Qp, Kp, Vtp, Xp);

  GemmArgs go;
  go.d[0] = GemmDesc{Xp, wob, bo, d_out, 2};
  go.d[1] = go.d[0];
  go.d[2] = go.d[0];
  gemm_bt<<<dim3(8, 32, 1), dim3(256), 0, stream>>>(go);
}

// Round 3
// 311.363 us; speedup vs baseline: 1.1615x; 1.1615x over previous
//
#include <hip/hip_runtime.h>
#include <hip/hip_bf16.h>
#include <stdint.h>

#define HN     16
#define DMODEL 1024
#define DKH    64
#define SEQL   4096

typedef __attribute__((ext_vector_type(8))) short bf16x8;
typedef __attribute__((ext_vector_type(4))) float f32x4;

typedef const __attribute__((address_space(1))) uint32_t gas_u32;
typedef __attribute__((address_space(3))) uint32_t las_u32;

// async global->LDS, 16B per lane; LDS dest = wave-uniform base + lane*16
__device__ __forceinline__ void gl_lds16(const void* g, void* l) {
  __builtin_amdgcn_global_load_lds((gas_u32*)g, (las_u32*)l, 16, 0, 0);
}

__device__ __forceinline__ unsigned short f2bf(float x) {
  uint32_t u = __float_as_uint(x);
  u = (u + 0x7fffu + ((u >> 16) & 1u)) >> 16;
  return (unsigned short)u;
}

__device__ __forceinline__ uint32_t cvt_pk_bf16(float lo, float hi) {
  uint32_t r;
  asm("v_cvt_pk_bf16_f32 %0, %1, %2" : "=v"(r) : "v"(lo), "v"(hi));
  return r;
}

// raw v_exp_f32 (2^x) — single trans-pipe instruction, no ocml wrapper
__device__ __forceinline__ float fast_exp2(float x) {
  float r;
  asm("v_exp_f32 %0, %1" : "=v"(r) : "v"(x));
  return r;
}

// ---------------- fp32 -> bf16 conversion (7 tensors fused) ----------------
struct CvtArgs {
  const float *q, *k, *v, *wq, *wk, *wv, *wo;
  unsigned short *qb, *kb, *vb, *wqb, *wkb, *wvb, *wob;
};

__global__ __launch_bounds__(256) void cvt_all(CvtArgs a) {
  const int stride = gridDim.x * blockDim.x;
  for (int v4 = blockIdx.x * blockDim.x + threadIdx.x; v4 < 4194304; v4 += stride) {
    const float* sp; unsigned short* dp; int idx;
    if      (v4 < 1048576) { sp = a.q;  dp = a.qb;  idx = v4; }
    else if (v4 < 2097152) { sp = a.k;  dp = a.kb;  idx = v4 - 1048576; }
    else if (v4 < 3145728) { sp = a.v;  dp = a.vb;  idx = v4 - 2097152; }
    else if (v4 < 3407872) { sp = a.wq; dp = a.wqb; idx = v4 - 3145728; }
    else if (v4 < 3670016) { sp = a.wk; dp = a.wkb; idx = v4 - 3407872; }
    else if (v4 < 3932160) { sp = a.wv; dp = a.wvb; idx = v4 - 3670016; }
    else                   { sp = a.wo; dp = a.wob; idx = v4 - 3932160; }
    float4 f = ((const float4*)sp)[idx];
    ushort4 o;
    o.x = f2bf(f.x); o.y = f2bf(f.y); o.z = f2bf(f.z); o.w = f2bf(f.w);
    ((ushort4*)dp)[idx] = o;
  }
}

// ---------------- GEMM: C = A * W^T + bias  (A:[M,K] bf16, W:[N,K] bf16) ----
// mode 0: bf16 C[M,N]; mode 1: bf16 C^T[N,M]; mode 2: f32 C[M,N]
struct GemmDesc {
  const unsigned short* A;
  const unsigned short* W;
  const float* bias;
  void* C;
  int mode;
};
struct GemmArgs { GemmDesc d[3]; };

__global__ __launch_bounds__(256) void gemm_bt(GemmArgs ga) {
  const GemmDesc gd = ga.d[blockIdx.z];
  constexpr int M = SEQL, N = DMODEL, K = DMODEL;
  __shared__ unsigned short As[128 * 64];
  __shared__ unsigned short Bs[128 * 64];
  const int tid = threadIdx.x;
  const int w = tid >> 6, lane = tid & 63;
  const int g16 = lane >> 4, l16 = lane & 15;
  const int wr = w >> 1, wc = w & 1;
  const int bm0 = blockIdx.y * 128, bn0 = blockIdx.x * 128;
  const int srow = tid >> 3, scc = tid & 7;

  f32x4 acc[4][4];
#pragma unroll
  for (int i = 0; i < 4; ++i)
#pragma unroll
    for (int j = 0; j < 4; ++j)
      acc[i][j] = (f32x4){0.f, 0.f, 0.f, 0.f};

  for (int k0 = 0; k0 < K; k0 += 64) {
#pragma unroll
    for (int i = 0; i < 4; ++i) {
      int row = i * 32 + srow;
      int sw = scc ^ (row & 7);
      gl_lds16(gd.A + (size_t)(bm0 + row) * K + k0 + sw * 8,
               (void*)(As + (i * 256 + w * 64) * 8));
      gl_lds16(gd.W + (size_t)(bn0 + row) * K + k0 + sw * 8,
               (void*)(Bs + (i * 256 + w * 64) * 8));
    }
    __syncthreads();
#pragma unroll
    for (int ks = 0; ks < 2; ++ks) {
      bf16x8 af[4], bfr[4];
#pragma unroll
      for (int mt = 0; mt < 4; ++mt) {
        int row = wr * 64 + mt * 16 + l16;
        af[mt] = *(const bf16x8*)&As[row * 64 + (((ks * 4 + g16) ^ (row & 7)) * 8)];
      }
#pragma unroll
      for (int nt = 0; nt < 4; ++nt) {
        int row = wc * 64 + nt * 16 + l16;
        bfr[nt] = *(const bf16x8*)&Bs[row * 64 + (((ks * 4 + g16) ^ (row & 7)) * 8)];
      }
#pragma unroll
      for (int mt = 0; mt < 4; ++mt)
#pragma unroll
        for (int nt = 0; nt < 4; ++nt)
          acc[mt][nt] = __builtin_amdgcn_mfma_f32_16x16x32_bf16(af[mt], bfr[nt], acc[mt][nt], 0, 0, 0);
    }
    __syncthreads();
  }

  // epilogue: C/D layout col=lane&15, row=(lane>>4)*4+reg
#pragma unroll
  for (int nt = 0; nt < 4; ++nt) {
    int col = bn0 + wc * 64 + nt * 16 + l16;
    float bcol = gd.bias[col];
#pragma unroll
    for (int mt = 0; mt < 4; ++mt) {
      int row0 = bm0 + wr * 64 + mt * 16 + g16 * 4;
      f32x4 a = acc[mt][nt];
      if (gd.mode == 0) {
        unsigned short* CB = (unsigned short*)gd.C;
#pragma unroll
        for (int r = 0; r < 4; ++r)
          CB[(size_t)(row0 + r) * N + col] = f2bf(a[r] + bcol);
      } else if (gd.mode == 1) {
        unsigned short* CT = (unsigned short*)gd.C;
        ushort4 pk;
        pk.x = f2bf(a[0] + bcol); pk.y = f2bf(a[1] + bcol);
        pk.z = f2bf(a[2] + bcol); pk.w = f2bf(a[3] + bcol);
        *(ushort4*)&CT[(size_t)col * M + row0] = pk;
      } else {
        float* CF = (float*)gd.C;
#pragma unroll
        for (int r = 0; r < 4; ++r)
          CF[(size_t)(row0 + r) * N + col] = a[r] + bcol;
      }
    }
  }
}

// ---------------- flash attention ----------------
// grid (SEQ/64, H); 4 waves/block; wave owns 16 q-rows; KV tile = 64.
// Swapped QK^T (S^T = K*Q^T) so lane (q=lane&15) holds a 16-score slice.
// 2-phase pipeline: STAGE(next) -> compute(cur) -> vmcnt(0) -> s_barrier.
// P-transpose via wave-private LDS (replaces 32 bpermutes).
__global__ __launch_bounds__(256) void attn_fwd(
    const unsigned short* __restrict__ Qm, const unsigned short* __restrict__ Km,
    const unsigned short* __restrict__ Vtm, unsigned short* __restrict__ Xm) {
  __shared__ __align__(16) unsigned short Ksm[2 * 4096];
  __shared__ __align__(16) unsigned short Vsm[2 * 4096];
  __shared__ __align__(16) unsigned short Psm[4096];
  const int tid = threadIdx.x;
  const int w = tid >> 6, lane = tid & 63;
  const int g = lane >> 4, qi = lane & 15;
  const int hb = blockIdx.y * DKH;
  const int q0 = blockIdx.x * 64 + w * 16;
  const int srow = tid >> 3, scc = tid & 7;
  const float CE = 0.18033688011112042f; // log2(e)/sqrt(64)
  const float THR = 66.5f;               // defer-max: 12 / CE

  // staging source pointers (tile 0), pre-swizzled chunk = scc ^ (row&7)
  const int r0 = srow, r1 = 32 + srow;
  const unsigned short* kp0 = Km + (size_t)r0 * DMODEL + hb + (scc ^ (r0 & 7)) * 8;
  const unsigned short* kp1 = Km + (size_t)r1 * DMODEL + hb + (scc ^ (r1 & 7)) * 8;
  const unsigned short* vp0 = Vtm + (size_t)(hb + r0) * SEQL + (scc ^ (r0 & 7)) * 8;
  const unsigned short* vp1 = Vtm + (size_t)(hb + r1) * SEQL + (scc ^ (r1 & 7)) * 8;
  unsigned short* kd0 = Ksm + (w * 64) * 8;
  unsigned short* kd1 = Ksm + (256 + w * 64) * 8;
  unsigned short* vd0 = Vsm + (w * 64) * 8;
  unsigned short* vd1 = Vsm + (256 + w * 64) * 8;

  // P-LDS addresses (elements), wave-private 1KB slice; element kv of row qi
  // lives at byte ((kv>>3)^(qi&7))*16 + (kv&7)*2 within the row.
  int pw[4], pr[2];
#pragma unroll
  for (int kvt = 0; kvt < 4; ++kvt)
    pw[kvt] = w * 1024 + qi * 64 + (((2 * kvt + (g >> 1)) ^ (qi & 7)) * 8) + (g & 1) * 4;
#pragma unroll
  for (int ks = 0; ks < 2; ++ks)
    pr[ks] = w * 1024 + qi * 64 + (((ks * 4 + g) ^ (qi & 7)) * 8);

  // Q as B-operand fragments: lane holds Q[q0+qi][k = ks*32 + g*8 + j]
  bf16x8 qf[2];
#pragma unroll
  for (int ks = 0; ks < 2; ++ks)
    qf[ks] = *(const bf16x8*)&Qm[(size_t)(q0 + qi) * DMODEL + hb + ks * 32 + g * 8];

  f32x4 oacc[4];
#pragma unroll
  for (int i = 0; i < 4; ++i) oacc[i] = (f32x4){0.f, 0.f, 0.f, 0.f};
  float mrun = -1e30f, lsum = 0.f;

  // prologue: stage tile 0 into buf 0
  gl_lds16(kp0, kd0); gl_lds16(kp1, kd1);
  gl_lds16(vp0, vd0); gl_lds16(vp1, vd1);
  asm volatile("s_waitcnt vmcnt(0)" ::: "memory");
  __builtin_amdgcn_s_barrier();

  int buf = 0;
  for (int t = 0; t < SEQL / 64; ++t) {
    // issue next-tile stage into buf^1 (last iter reloads tile 0, harmless)
    const int tn = (t + 1) & 63;
    const int bo = (buf ^ 1) * 4096;
    gl_lds16(kp0 + (size_t)tn * 64 * DMODEL, kd0 + bo);
    gl_lds16(kp1 + (size_t)tn * 64 * DMODEL, kd1 + bo);
    gl_lds16(vp0 + tn * 64, vd0 + bo);
    gl_lds16(vp1 + tn * 64, vd1 + bo);

    const unsigned short* Kb = Ksm + buf * 4096;
    const unsigned short* Vb = Vsm + buf * 4096;

    // S^T = K * Q^T : 4 kv-tiles of 16
    f32x4 sv[4];
#pragma unroll
    for (int kvt = 0; kvt < 4; ++kvt) sv[kvt] = (f32x4){0.f, 0.f, 0.f, 0.f};
    __builtin_amdgcn_s_setprio(1);
#pragma unroll
    for (int kvt = 0; kvt < 4; ++kvt) {
      int row = kvt * 16 + qi;
      bf16x8 ka0 = *(const bf16x8*)&Kb[row * 64 + (((0 + g) ^ (row & 7)) * 8)];
      bf16x8 ka1 = *(const bf16x8*)&Kb[row * 64 + (((4 + g) ^ (row & 7)) * 8)];
      sv[kvt] = __builtin_amdgcn_mfma_f32_16x16x32_bf16(ka0, qf[0], sv[kvt], 0, 0, 0);
      sv[kvt] = __builtin_amdgcn_mfma_f32_16x16x32_bf16(ka1, qf[1], sv[kvt], 0, 0, 0);
    }
    __builtin_amdgcn_s_setprio(0);

    // row max over this tile (lane owns q=qi; kv = kvt*16 + g*4 + r)
    float tmax = sv[0][0];
#pragma unroll
    for (int kvt = 0; kvt < 4; ++kvt)
#pragma unroll
      for (int r = 0; r < 4; ++r) tmax = fmaxf(tmax, sv[kvt][r]);
    tmax = fmaxf(tmax, __shfl_xor(tmax, 16));
    tmax = fmaxf(tmax, __shfl_xor(tmax, 32));

    // defer-max: only rescale when the running max grew materially
    if (__any(tmax - mrun > THR)) {
      float mnew = fmaxf(mrun, tmax);
      float alpha = fast_exp2((mrun - mnew) * CE);
      lsum *= alpha;
#pragma unroll
      for (int r = 0; r < 4; ++r) {
        float ar = __shfl(alpha, (lane & 48) + g * 4 + r);
#pragma unroll
        for (int dg = 0; dg < 4; ++dg) oacc[dg][r] *= ar;
      }
      mrun = mnew;
    }

    // P = exp2((S - m)*CE), bounded by 2^12; row-sum
    float p[16];
    float psum = 0.f;
#pragma unroll
    for (int kvt = 0; kvt < 4; ++kvt)
#pragma unroll
      for (int r = 0; r < 4; ++r) {
        float pv = fast_exp2((sv[kvt][r] - mrun) * CE);
        p[kvt * 4 + r] = pv;
        psum += pv;
      }
    psum += __shfl_xor(psum, 16);
    psum += __shfl_xor(psum, 32);
    lsum += psum;

    // P-transpose through wave-private LDS (write b64 x4, read b128 x2)
#pragma unroll
    for (int kvt = 0; kvt < 4; ++kvt) {
      uint2 pk;
      pk.x = cvt_pk_bf16(p[kvt * 4 + 0], p[kvt * 4 + 1]);
      pk.y = cvt_pk_bf16(p[kvt * 4 + 2], p[kvt * 4 + 3]);
      *(uint2*)&Psm[pw[kvt]] = pk;
    }
    bf16x8 pa0 = *(const bf16x8*)&Psm[pr[0]];
    bf16x8 pa1 = *(const bf16x8*)&Psm[pr[1]];

    // PV: O += P * V  (B-operand from Vt tile rows = d)
    __builtin_amdgcn_s_setprio(1);
#pragma unroll
    for (int dg = 0; dg < 4; ++dg) {
      int row = dg * 16 + qi;
      bf16x8 vb0 = *(const bf16x8*)&Vb[row * 64 + (((0 + g) ^ (row & 7)) * 8)];
      bf16x8 vb1 = *(const bf16x8*)&Vb[row * 64 + (((4 + g) ^ (row & 7)) * 8)];
      oacc[dg] = __builtin_amdgcn_mfma_f32_16x16x32_bf16(pa0, vb0, oacc[dg], 0, 0, 0);
      oacc[dg] = __builtin_amdgcn_mfma_f32_16x16x32_bf16(pa1, vb1, oacc[dg], 0, 0, 0);
    }
    __builtin_amdgcn_s_setprio(0);

    asm volatile("s_waitcnt vmcnt(0)" ::: "memory");
    __builtin_amdgcn_s_barrier();
    buf ^= 1;
  }

  float linv = 1.f / lsum;
#pragma unroll
  for (int r = 0; r < 4; ++r) {
    float lr = __shfl(linv, (lane & 48) + g * 4 + r);
    int row = q0 + g * 4 + r;
#pragma unroll
    for (int dg = 0; dg < 4; ++dg)
      Xm[(size_t)row * DMODEL + hb + dg * 16 + qi] = f2bf(oacc[dg][r] * lr);
  }
}

// ---------------- launch ----------------
extern "C" void kernel_launch(void* const* d_in, const int* in_sizes, int n_in,
                              void* d_out, int out_size, void* d_ws, size_t ws_size,
                              hipStream_t stream) {
  const float* query = (const float*)d_in[0];
  const float* key_  = (const float*)d_in[1];
  const float* value = (const float*)d_in[2];
  const float* Wq = (const float*)d_in[3];
  const float* bq = (const float*)d_in[4];
  const float* Wk = (const float*)d_in[5];
  const float* bk = (const float*)d_in[6];
  const float* Wv = (const float*)d_in[7];
  const float* bv = (const float*)d_in[8];
  const float* Wo = (const float*)d_in[9];
  const float* bo = (const float*)d_in[10];

  char* ws = (char*)d_ws;
  const size_t MB = 1024 * 1024;
  unsigned short* qb  = (unsigned short*)(ws + 0 * MB);
  unsigned short* kb  = (unsigned short*)(ws + 8 * MB);
  unsigned short* vb  = (unsigned short*)(ws + 16 * MB);
  unsigned short* wqb = (unsigned short*)(ws + 24 * MB);
  unsigned short* wkb = (unsigned short*)(ws + 26 * MB);
  unsigned short* wvb = (unsigned short*)(ws + 28 * MB);
  unsigned short* wob = (unsigned short*)(ws + 30 * MB);
  unsigned short* Qp  = (unsigned short*)(ws + 32 * MB);
  unsigned short* Kp  = (unsigned short*)(ws + 40 * MB);
  unsigned short* Vtp = (unsigned short*)(ws + 48 * MB);
  unsigned short* Xp  = (unsigned short*)(ws + 56 * MB);

  CvtArgs ca{query, key_, value, Wq, Wk, Wv, Wo, qb, kb, vb, wqb, wkb, wvb, wob};
  cvt_all<<<dim3(2048), dim3(256), 0, stream>>>(ca);

  GemmArgs gp;
  gp.d[0] = GemmDesc{qb, wqb, bq, (void*)Qp, 0};
  gp.d[1] = GemmDesc{kb, wkb, bk, (void*)Kp, 0};
  gp.d[2] = GemmDesc{vb, wvb, bv, (void*)Vtp, 1}; // V written transposed [d][s]
  gemm_bt<<<dim3(8, 32, 3), dim3(256), 0, stream>>>(gp);

  attn_fwd<<<dim3(SEQL / 64, HN), dim3(256), 0, stream>>>(Qp, Kp, Vtp, Xp);

  GemmArgs go;
  go.d[0] = GemmDesc{Xp, wob, bo, d_out, 2};
  go.d[1] = go.d[0];
  go.d[2] = go.d[0];
  gemm_bt<<<dim3(8, 32, 1), dim3(256), 0, stream>>>(go);
}

// Round 4
// 290.563 us; speedup vs baseline: 1.2446x; 1.0716x over previous
//
#include <hip/hip_runtime.h>
#include <hip/hip_bf16.h>
#include <stdint.h>

#define HN     16
#define DMODEL 1024
#define DKH    64
#define SEQL   4096

typedef __attribute__((ext_vector_type(8))) short bf16x8;
typedef __attribute__((ext_vector_type(4))) float f32x4;

typedef const __attribute__((address_space(1))) uint32_t gas_u32;
typedef __attribute__((address_space(3))) uint32_t las_u32;

// async global->LDS, 16B per lane; LDS dest = wave-uniform base + lane*16
__device__ __forceinline__ void gl_lds16(const void* g, void* l) {
  __builtin_amdgcn_global_load_lds((gas_u32*)g, (las_u32*)l, 16, 0, 0);
}

__device__ __forceinline__ unsigned short f2bf(float x) {
  uint32_t u = __float_as_uint(x);
  u = (u + 0x7fffu + ((u >> 16) & 1u)) >> 16;
  return (unsigned short)u;
}

__device__ __forceinline__ uint32_t cvt_pk_bf16(float lo, float hi) {
  uint32_t r;
  asm("v_cvt_pk_bf16_f32 %0, %1, %2" : "=v"(r) : "v"(lo), "v"(hi));
  return r;
}

// raw v_exp_f32 (2^x) — single trans-pipe instruction, no ocml wrapper
__device__ __forceinline__ float fast_exp2(float x) {
  float r;
  asm("v_exp_f32 %0, %1" : "=v"(r) : "v"(x));
  return r;
}

// ---------------- fp32 -> bf16 conversion (7 tensors fused) ----------------
struct CvtArgs {
  const float *q, *k, *v, *wq, *wk, *wv, *wo;
  unsigned short *qb, *kb, *vb, *wqb, *wkb, *wvb, *wob;
};

__global__ __launch_bounds__(256) void cvt_all(CvtArgs a) {
  const int stride = gridDim.x * blockDim.x;
  for (int v4 = blockIdx.x * blockDim.x + threadIdx.x; v4 < 4194304; v4 += stride) {
    const float* sp; unsigned short* dp; int idx;
    if      (v4 < 1048576) { sp = a.q;  dp = a.qb;  idx = v4; }
    else if (v4 < 2097152) { sp = a.k;  dp = a.kb;  idx = v4 - 1048576; }
    else if (v4 < 3145728) { sp = a.v;  dp = a.vb;  idx = v4 - 2097152; }
    else if (v4 < 3407872) { sp = a.wq; dp = a.wqb; idx = v4 - 3145728; }
    else if (v4 < 3670016) { sp = a.wk; dp = a.wkb; idx = v4 - 3407872; }
    else if (v4 < 3932160) { sp = a.wv; dp = a.wvb; idx = v4 - 3670016; }
    else                   { sp = a.wo; dp = a.wob; idx = v4 - 3932160; }
    float4 f = ((const float4*)sp)[idx];
    ushort4 o;
    o.x = f2bf(f.x); o.y = f2bf(f.y); o.z = f2bf(f.z); o.w = f2bf(f.w);
    ((ushort4*)dp)[idx] = o;
  }
}

// ---------------- GEMM: C = (A * W^T + bias)*scale  ------------------------
// mode 0: bf16 C[M,N]; mode 1: bf16 C^T[N,M]; mode 2: f32 C[M,N]
struct GemmDesc {
  const unsigned short* A;
  const unsigned short* W;
  const float* bias;
  void* C;
  int mode;
  float scale;
};
struct GemmArgs { GemmDesc d[3]; };

__global__ __launch_bounds__(256) void gemm_bt(GemmArgs ga) {
  const GemmDesc gd = ga.d[blockIdx.z];
  constexpr int M = SEQL, N = DMODEL, K = DMODEL;
  __shared__ unsigned short As[128 * 64];
  __shared__ unsigned short Bs[128 * 64];
  const int tid = threadIdx.x;
  const int w = tid >> 6, lane = tid & 63;
  const int g16 = lane >> 4, l16 = lane & 15;
  const int wr = w >> 1, wc = w & 1;
  const int bm0 = blockIdx.y * 128, bn0 = blockIdx.x * 128;
  const int srow = tid >> 3, scc = tid & 7;

  f32x4 acc[4][4];
#pragma unroll
  for (int i = 0; i < 4; ++i)
#pragma unroll
    for (int j = 0; j < 4; ++j)
      acc[i][j] = (f32x4){0.f, 0.f, 0.f, 0.f};

  for (int k0 = 0; k0 < K; k0 += 64) {
#pragma unroll
    for (int i = 0; i < 4; ++i) {
      int row = i * 32 + srow;
      int sw = scc ^ (row & 7);
      gl_lds16(gd.A + (size_t)(bm0 + row) * K + k0 + sw * 8,
               (void*)(As + (i * 256 + w * 64) * 8));
      gl_lds16(gd.W + (size_t)(bn0 + row) * K + k0 + sw * 8,
               (void*)(Bs + (i * 256 + w * 64) * 8));
    }
    __syncthreads();
#pragma unroll
    for (int ks = 0; ks < 2; ++ks) {
      bf16x8 af[4], bfr[4];
#pragma unroll
      for (int mt = 0; mt < 4; ++mt) {
        int row = wr * 64 + mt * 16 + l16;
        af[mt] = *(const bf16x8*)&As[row * 64 + (((ks * 4 + g16) ^ (row & 7)) * 8)];
      }
#pragma unroll
      for (int nt = 0; nt < 4; ++nt) {
        int row = wc * 64 + nt * 16 + l16;
        bfr[nt] = *(const bf16x8*)&Bs[row * 64 + (((ks * 4 + g16) ^ (row & 7)) * 8)];
      }
#pragma unroll
      for (int mt = 0; mt < 4; ++mt)
#pragma unroll
        for (int nt = 0; nt < 4; ++nt)
          acc[mt][nt] = __builtin_amdgcn_mfma_f32_16x16x32_bf16(af[mt], bfr[nt], acc[mt][nt], 0, 0, 0);
    }
    __syncthreads();
  }

  // epilogue: C/D layout col=lane&15, row=(lane>>4)*4+reg
#pragma unroll
  for (int nt = 0; nt < 4; ++nt) {
    int col = bn0 + wc * 64 + nt * 16 + l16;
    float bcol = gd.bias[col];
#pragma unroll
    for (int mt = 0; mt < 4; ++mt) {
      int row0 = bm0 + wr * 64 + mt * 16 + g16 * 4;
      f32x4 a = acc[mt][nt];
      if (gd.mode == 0) {
        unsigned short* CB = (unsigned short*)gd.C;
#pragma unroll
        for (int r = 0; r < 4; ++r)
          CB[(size_t)(row0 + r) * N + col] = f2bf((a[r] + bcol) * gd.scale);
      } else if (gd.mode == 1) {
        unsigned short* CT = (unsigned short*)gd.C;
        ushort4 pk;
        pk.x = f2bf(a[0] + bcol); pk.y = f2bf(a[1] + bcol);
        pk.z = f2bf(a[2] + bcol); pk.w = f2bf(a[3] + bcol);
        *(ushort4*)&CT[(size_t)col * M + row0] = pk;
      } else {
        float* CF = (float*)gd.C;
#pragma unroll
        for (int r = 0; r < 4; ++r)
          CF[(size_t)(row0 + r) * N + col] = a[r] + bcol;
      }
    }
  }
}

// ---------------- flash attention ----------------
// grid (SEQ/64, H); 4 waves/block; wave owns 16 q-rows; KV tile = 64.
// Q pre-scaled by log2(e)/sqrt(dk) so exp2 needs only a subtract.
// Swapped QK^T (S^T = K*Q^T); row-sum via ones-MFMA (denominator lands in
// the same D-layout as oacc -> no epilogue shuffles). All LDS read addrs are
// loop-invariant bases + compile-time offsets (t-loop unrolled x2 over buf).
__global__ __launch_bounds__(256, 3) void attn_fwd(
    const unsigned short* __restrict__ Qm, const unsigned short* __restrict__ Km,
    const unsigned short* __restrict__ Vtm, unsigned short* __restrict__ Xm) {
  __shared__ __align__(16) unsigned short Ksm[2 * 4096];
  __shared__ __align__(16) unsigned short Vsm[2 * 4096];
  __shared__ __align__(16) unsigned short Psm[4096];
  const int tid = threadIdx.x;
  const int w = tid >> 6, lane = tid & 63;
  const int g = lane >> 4, qi = lane & 15;
  const int hb = blockIdx.y * DKH;
  const int q0 = blockIdx.x * 64 + w * 16;
  const int srow = tid >> 3, scc = tid & 7;
  const float THR = 12.0f;

  // staging source pointers (tile 0), pre-swizzled chunk = scc ^ (row&7)
  const int r0 = srow, r1 = 32 + srow;
  const unsigned short* kp0 = Km + (size_t)r0 * DMODEL + hb + (scc ^ (r0 & 7)) * 8;
  const unsigned short* kp1 = Km + (size_t)r1 * DMODEL + hb + (scc ^ (r1 & 7)) * 8;
  const unsigned short* vp0 = Vtm + (size_t)(hb + r0) * SEQL + (scc ^ (r0 & 7)) * 8;
  const unsigned short* vp1 = Vtm + (size_t)(hb + r1) * SEQL + (scc ^ (r1 & 7)) * 8;
  unsigned short* kd0 = Ksm + (w * 64) * 8;
  unsigned short* kd1 = Ksm + (256 + w * 64) * 8;
  unsigned short* vd0 = Vsm + (w * 64) * 8;
  unsigned short* vd1 = Vsm + (256 + w * 64) * 8;

  // loop-invariant LDS read bases (row = sub*16 + qi => row&7 == qi&7, so the
  // XOR chunk is sub-independent; sub & buf become ds_read immediates)
  const unsigned short* kb0 = &Ksm[qi * 64 + (((0 + g) ^ (qi & 7)) * 8)];
  const unsigned short* kb1 = &Ksm[qi * 64 + (((4 + g) ^ (qi & 7)) * 8)];
  const unsigned short* vrb0 = &Vsm[qi * 64 + (((0 + g) ^ (qi & 7)) * 8)];
  const unsigned short* vrb1 = &Vsm[qi * 64 + (((4 + g) ^ (qi & 7)) * 8)];

  // P-LDS addresses (elements), wave-private 1KB slice
  int pw0 = w * 1024 + qi * 64 + (((0 + (g >> 1)) ^ (qi & 7)) * 8) + (g & 1) * 4;
  int pw1 = w * 1024 + qi * 64 + (((2 + (g >> 1)) ^ (qi & 7)) * 8) + (g & 1) * 4;
  int pw2 = w * 1024 + qi * 64 + (((4 + (g >> 1)) ^ (qi & 7)) * 8) + (g & 1) * 4;
  int pw3 = w * 1024 + qi * 64 + (((6 + (g >> 1)) ^ (qi & 7)) * 8) + (g & 1) * 4;
  const unsigned short* prb0 = &Psm[w * 1024 + qi * 64 + (((0 + g) ^ (qi & 7)) * 8)];
  const unsigned short* prb1 = &Psm[w * 1024 + qi * 64 + (((4 + g) ^ (qi & 7)) * 8)];

  // ones B-fragment for the denominator MFMA
  union { uint32_t u[4]; bf16x8 v; } onef;
  onef.u[0] = onef.u[1] = onef.u[2] = onef.u[3] = 0x3F803F80u;

  // Q as B-operand fragments: lane holds Q[q0+qi][k = ks*32 + g*8 + j]
  bf16x8 qf[2];
#pragma unroll
  for (int ks = 0; ks < 2; ++ks)
    qf[ks] = *(const bf16x8*)&Qm[(size_t)(q0 + qi) * DMODEL + hb + ks * 32 + g * 8];

  f32x4 oacc[4];
#pragma unroll
  for (int i = 0; i < 4; ++i) oacc[i] = (f32x4){0.f, 0.f, 0.f, 0.f};
  f32x4 lacc = (f32x4){0.f, 0.f, 0.f, 0.f};
  float mrun = -1e30f;

  // prologue: stage tile 0 into buf 0
  gl_lds16(kp0, kd0); gl_lds16(kp1, kd1);
  gl_lds16(vp0, vd0); gl_lds16(vp1, vd1);
  kp0 += 64 * DMODEL; kp1 += 64 * DMODEL; vp0 += 64; vp1 += 64;
  asm volatile("s_waitcnt vmcnt(0)" ::: "memory");
  __builtin_amdgcn_s_barrier();

#define ATTN_STEP(BUF)                                                         \
  do {                                                                         \
    /* prefetch next tile into buf BUF^1 (final iter overruns harmlessly) */   \
    gl_lds16(kp0, kd0 + ((BUF) ^ 1) * 4096);                                   \
    gl_lds16(kp1, kd1 + ((BUF) ^ 1) * 4096);                                   \
    gl_lds16(vp0, vd0 + ((BUF) ^ 1) * 4096);                                   \
    gl_lds16(vp1, vd1 + ((BUF) ^ 1) * 4096);                                   \
    kp0 += 64 * DMODEL; kp1 += 64 * DMODEL; vp0 += 64; vp1 += 64;              \
    f32x4 sv[4];                                                               \
    _Pragma("unroll")                                                          \
    for (int kvt = 0; kvt < 4; ++kvt) sv[kvt] = (f32x4){0.f, 0.f, 0.f, 0.f};   \
    __builtin_amdgcn_s_setprio(1);                                             \
    _Pragma("unroll")                                                          \
    for (int kvt = 0; kvt < 4; ++kvt) {                                        \
      bf16x8 ka0 = *(const bf16x8*)(kb0 + (BUF) * 4096 + kvt * 1024);          \
      bf16x8 ka1 = *(const bf16x8*)(kb1 + (BUF) * 4096 + kvt * 1024);          \
      sv[kvt] = __builtin_amdgcn_mfma_f32_16x16x32_bf16(ka0, qf[0], sv[kvt], 0, 0, 0); \
      sv[kvt] = __builtin_amdgcn_mfma_f32_16x16x32_bf16(ka1, qf[1], sv[kvt], 0, 0, 0); \
    }                                                                          \
    __builtin_amdgcn_s_setprio(0);                                             \
    float tmax = sv[0][0];                                                     \
    _Pragma("unroll")                                                          \
    for (int kvt = 0; kvt < 4; ++kvt)                                          \
      _Pragma("unroll")                                                        \
      for (int r = 0; r < 4; ++r) tmax = fmaxf(tmax, sv[kvt][r]);              \
    tmax = fmaxf(tmax, __shfl_xor(tmax, 16));                                  \
    tmax = fmaxf(tmax, __shfl_xor(tmax, 32));                                  \
    if (__any(tmax - mrun > THR)) {                                            \
      float mnew = fmaxf(mrun, tmax);                                          \
      float alpha = fast_exp2(mrun - mnew);                                    \
      _Pragma("unroll")                                                        \
      for (int r = 0; r < 4; ++r) {                                            \
        float ar = __shfl(alpha, (lane & 48) + g * 4 + r);                     \
        lacc[r] *= ar;                                                         \
        _Pragma("unroll")                                                      \
        for (int dg = 0; dg < 4; ++dg) oacc[dg][r] *= ar;                      \
      }                                                                        \
      mrun = mnew;                                                             \
    }                                                                          \
    float p[16];                                                               \
    _Pragma("unroll")                                                          \
    for (int kvt = 0; kvt < 4; ++kvt)                                          \
      _Pragma("unroll")                                                        \
      for (int r = 0; r < 4; ++r)                                              \
        p[kvt * 4 + r] = fast_exp2(sv[kvt][r] - mrun);                         \
    uint2 pk;                                                                  \
    pk.x = cvt_pk_bf16(p[0], p[1]);  pk.y = cvt_pk_bf16(p[2], p[3]);           \
    *(uint2*)&Psm[pw0] = pk;                                                   \
    pk.x = cvt_pk_bf16(p[4], p[5]);  pk.y = cvt_pk_bf16(p[6], p[7]);           \
    *(uint2*)&Psm[pw1] = pk;                                                   \
    pk.x = cvt_pk_bf16(p[8], p[9]);  pk.y = cvt_pk_bf16(p[10], p[11]);         \
    *(uint2*)&Psm[pw2] = pk;                                                   \
    pk.x = cvt_pk_bf16(p[12], p[13]); pk.y = cvt_pk_bf16(p[14], p[15]);        \
    *(uint2*)&Psm[pw3] = pk;                                                   \
    bf16x8 pa0 = *(const bf16x8*)prb0;                                         \
    bf16x8 pa1 = *(const bf16x8*)prb1;                                         \
    __builtin_amdgcn_s_setprio(1);                                             \
    lacc = __builtin_amdgcn_mfma_f32_16x16x32_bf16(pa0, onef.v, lacc, 0, 0, 0);\
    lacc = __builtin_amdgcn_mfma_f32_16x16x32_bf16(pa1, onef.v, lacc, 0, 0, 0);\
    _Pragma("unroll")                                                          \
    for (int dg = 0; dg < 4; ++dg) {                                           \
      bf16x8 vb0 = *(const bf16x8*)(vrb0 + (BUF) * 4096 + dg * 1024);          \
      bf16x8 vb1 = *(const bf16x8*)(vrb1 + (BUF) * 4096 + dg * 1024);          \
      oacc[dg] = __builtin_amdgcn_mfma_f32_16x16x32_bf16(pa0, vb0, oacc[dg], 0, 0, 0); \
      oacc[dg] = __builtin_amdgcn_mfma_f32_16x16x32_bf16(pa1, vb1, oacc[dg], 0, 0, 0); \
    }                                                                          \
    __builtin_amdgcn_s_setprio(0);                                             \
    asm volatile("s_waitcnt vmcnt(0)" ::: "memory");                           \
    __builtin_amdgcn_s_barrier();                                              \
  } while (0)

  for (int tt = 0; tt < SEQL / 128; ++tt) {
    ATTN_STEP(0);
    ATTN_STEP(1);
  }
#undef ATTN_STEP

#pragma unroll
  for (int r = 0; r < 4; ++r) {
    float inv = 1.f / lacc[r];
    int row = q0 + g * 4 + r;
#pragma unroll
    for (int dg = 0; dg < 4; ++dg)
      Xm[(size_t)row * DMODEL + hb + dg * 16 + qi] = f2bf(oacc[dg][r] * inv);
  }
}

// ---------------- launch ----------------
extern "C" void kernel_launch(void* const* d_in, const int* in_sizes, int n_in,
                              void* d_out, int out_size, void* d_ws, size_t ws_size,
                              hipStream_t stream) {
  const float* query = (const float*)d_in[0];
  const float* key_  = (const float*)d_in[1];
  const float* value = (const float*)d_in[2];
  const float* Wq = (const float*)d_in[3];
  const float* bq = (const float*)d_in[4];
  const float* Wk = (const float*)d_in[5];
  const float* bk = (const float*)d_in[6];
  const float* Wv = (const float*)d_in[7];
  const float* bv = (const float*)d_in[8];
  const float* Wo = (const float*)d_in[9];
  const float* bo = (const float*)d_in[10];

  char* ws = (char*)d_ws;
  const size_t MB = 1024 * 1024;
  unsigned short* qb  = (unsigned short*)(ws + 0 * MB);
  unsigned short* kb  = (unsigned short*)(ws + 8 * MB);
  unsigned short* vb  = (unsigned short*)(ws + 16 * MB);
  unsigned short* wqb = (unsigned short*)(ws + 24 * MB);
  unsigned short* wkb = (unsigned short*)(ws + 26 * MB);
  unsigned short* wvb = (unsigned short*)(ws + 28 * MB);
  unsigned short* wob = (unsigned short*)(ws + 30 * MB);
  unsigned short* Qp  = (unsigned short*)(ws + 32 * MB);
  unsigned short* Kp  = (unsigned short*)(ws + 40 * MB);
  unsigned short* Vtp = (unsigned short*)(ws + 48 * MB);
  unsigned short* Xp  = (unsigned short*)(ws + 56 * MB);

  CvtArgs ca{query, key_, value, Wq, Wk, Wv, Wo, qb, kb, vb, wqb, wkb, wvb, wob};
  cvt_all<<<dim3(2048), dim3(256), 0, stream>>>(ca);

  const float CE = 0.18033688011112042f; // log2(e)/sqrt(64)
  GemmArgs gp;
  gp.d[0] = GemmDesc{qb, wqb, bq, (void*)Qp, 0, CE};   // Q pre-scaled
  gp.d[1] = GemmDesc{kb, wkb, bk, (void*)Kp, 0, 1.0f};
  gp.d[2] = GemmDesc{vb, wvb, bv, (void*)Vtp, 1, 1.0f}; // V transposed [d][s]
  gemm_bt<<<dim3(8, 32, 3), dim3(256), 0, stream>>>(gp);

  attn_fwd<<<dim3(SEQL / 64, HN), dim3(256), 0, stream>>>(Qp, Kp, Vtp, Xp);

  GemmArgs go;
  go.d[0] = GemmDesc{Xp, wob, bo, d_out, 2, 1.0f};
  go.d[1] = go.d[0];
  go.d[2] = go.d[0];
  gemm_bt<<<dim3(8, 32, 1), dim3(256), 0, stream>>>(go);
}

// Round 5
// 280.087 us; speedup vs baseline: 1.2912x; 1.0374x over previous
//
#include <hip/hip_runtime.h>
#include <hip/hip_bf16.h>
#include <stdint.h>

#define HN     16
#define DMODEL 1024
#define DKH    64
#define SEQL   4096

typedef __attribute__((ext_vector_type(8))) short bf16x8;
typedef __attribute__((ext_vector_type(4))) float f32x4;

typedef const __attribute__((address_space(1))) uint32_t gas_u32;
typedef __attribute__((address_space(3))) uint32_t las_u32;

// async global->LDS, 16B per lane; LDS dest = wave-uniform base + lane*16
__device__ __forceinline__ void gl_lds16(const void* g, void* l) {
  __builtin_amdgcn_global_load_lds((gas_u32*)g, (las_u32*)l, 16, 0, 0);
}

__device__ __forceinline__ unsigned short f2bf(float x) {
  uint32_t u = __float_as_uint(x);
  u = (u + 0x7fffu + ((u >> 16) & 1u)) >> 16;
  return (unsigned short)u;
}

__device__ __forceinline__ uint32_t cvt_pk_bf16(float lo, float hi) {
  uint32_t r;
  asm("v_cvt_pk_bf16_f32 %0, %1, %2" : "=v"(r) : "v"(lo), "v"(hi));
  return r;
}

// raw v_exp_f32 (2^x) — single trans-pipe instruction, no ocml wrapper
__device__ __forceinline__ float fast_exp2(float x) {
  float r;
  asm("v_exp_f32 %0, %1" : "=v"(r) : "v"(x));
  return r;
}

// ---------------- fp32 -> bf16 conversion (7 tensors fused) ----------------
struct CvtArgs {
  const float *q, *k, *v, *wq, *wk, *wv, *wo;
  unsigned short *qb, *kb, *vb, *wqb, *wkb, *wvb, *wob;
};

__global__ __launch_bounds__(256) void cvt_all(CvtArgs a) {
  const int stride = gridDim.x * blockDim.x;
  for (int v4 = blockIdx.x * blockDim.x + threadIdx.x; v4 < 4194304; v4 += stride) {
    const float* sp; unsigned short* dp; int idx;
    if      (v4 < 1048576) { sp = a.q;  dp = a.qb;  idx = v4; }
    else if (v4 < 2097152) { sp = a.k;  dp = a.kb;  idx = v4 - 1048576; }
    else if (v4 < 3145728) { sp = a.v;  dp = a.vb;  idx = v4 - 2097152; }
    else if (v4 < 3407872) { sp = a.wq; dp = a.wqb; idx = v4 - 3145728; }
    else if (v4 < 3670016) { sp = a.wk; dp = a.wkb; idx = v4 - 3407872; }
    else if (v4 < 3932160) { sp = a.wv; dp = a.wvb; idx = v4 - 3670016; }
    else                   { sp = a.wo; dp = a.wob; idx = v4 - 3932160; }
    float4 f = ((const float4*)sp)[idx];
    ushort4 o;
    o.x = f2bf(f.x); o.y = f2bf(f.y); o.z = f2bf(f.z); o.w = f2bf(f.w);
    ((ushort4*)dp)[idx] = o;
  }
}

// ---------------- GEMM 128x128: C = (A * W^T + bias)*scale ------------------
// mode 0: bf16 C[M,N]; mode 1: bf16 C^T[N,M]
struct GemmDesc {
  const unsigned short* A;
  const unsigned short* W;
  const float* bias;
  void* C;
  int mode;
  float scale;
};
struct GemmArgs { GemmDesc d[3]; };

__global__ __launch_bounds__(256) void gemm_bt(GemmArgs ga) {
  const GemmDesc gd = ga.d[blockIdx.z];
  constexpr int M = SEQL, N = DMODEL, K = DMODEL;
  __shared__ unsigned short As[128 * 64];
  __shared__ unsigned short Bs[128 * 64];
  const int tid = threadIdx.x;
  const int w = tid >> 6, lane = tid & 63;
  const int g16 = lane >> 4, l16 = lane & 15;
  const int wr = w >> 1, wc = w & 1;
  const int bm0 = blockIdx.y * 128, bn0 = blockIdx.x * 128;
  const int srow = tid >> 3, scc = tid & 7;

  f32x4 acc[4][4];
#pragma unroll
  for (int i = 0; i < 4; ++i)
#pragma unroll
    for (int j = 0; j < 4; ++j)
      acc[i][j] = (f32x4){0.f, 0.f, 0.f, 0.f};

  for (int k0 = 0; k0 < K; k0 += 64) {
#pragma unroll
    for (int i = 0; i < 4; ++i) {
      int row = i * 32 + srow;
      int sw = scc ^ (row & 7);
      gl_lds16(gd.A + (size_t)(bm0 + row) * K + k0 + sw * 8,
               (void*)(As + (i * 256 + w * 64) * 8));
      gl_lds16(gd.W + (size_t)(bn0 + row) * K + k0 + sw * 8,
               (void*)(Bs + (i * 256 + w * 64) * 8));
    }
    __syncthreads();
#pragma unroll
    for (int ks = 0; ks < 2; ++ks) {
      bf16x8 af[4], bfr[4];
#pragma unroll
      for (int mt = 0; mt < 4; ++mt) {
        int row = wr * 64 + mt * 16 + l16;
        af[mt] = *(const bf16x8*)&As[row * 64 + (((ks * 4 + g16) ^ (row & 7)) * 8)];
      }
#pragma unroll
      for (int nt = 0; nt < 4; ++nt) {
        int row = wc * 64 + nt * 16 + l16;
        bfr[nt] = *(const bf16x8*)&Bs[row * 64 + (((ks * 4 + g16) ^ (row & 7)) * 8)];
      }
#pragma unroll
      for (int mt = 0; mt < 4; ++mt)
#pragma unroll
        for (int nt = 0; nt < 4; ++nt)
          acc[mt][nt] = __builtin_amdgcn_mfma_f32_16x16x32_bf16(af[mt], bfr[nt], acc[mt][nt], 0, 0, 0);
    }
    __syncthreads();
  }

  // epilogue: C/D layout col=lane&15, row=(lane>>4)*4+reg
#pragma unroll
  for (int nt = 0; nt < 4; ++nt) {
    int col = bn0 + wc * 64 + nt * 16 + l16;
    float bcol = gd.bias[col];
#pragma unroll
    for (int mt = 0; mt < 4; ++mt) {
      int row0 = bm0 + wr * 64 + mt * 16 + g16 * 4;
      f32x4 a = acc[mt][nt];
      if (gd.mode == 0) {
        unsigned short* CB = (unsigned short*)gd.C;
#pragma unroll
        for (int r = 0; r < 4; ++r)
          CB[(size_t)(row0 + r) * N + col] = f2bf((a[r] + bcol) * gd.scale);
      } else {
        unsigned short* CT = (unsigned short*)gd.C;
        ushort4 pk;
        pk.x = f2bf(a[0] + bcol); pk.y = f2bf(a[1] + bcol);
        pk.z = f2bf(a[2] + bcol); pk.w = f2bf(a[3] + bcol);
        *(ushort4*)&CT[(size_t)col * M + row0] = pk;
      }
    }
  }
}

// ---------------- GEMM 128x64 f32-out (O-projection) ------------------------
// 512 blocks (2/CU) vs 256 for the 128x128 tiling — fixes the latency-bound
// single-wave-per-SIMD regime of the final projection.
__global__ __launch_bounds__(256) void gemm_o(
    const unsigned short* __restrict__ A, const unsigned short* __restrict__ W,
    const float* __restrict__ bias, float* __restrict__ C) {
  constexpr int N = DMODEL, K = DMODEL;
  __shared__ unsigned short As[128 * 64];
  __shared__ unsigned short Bs[64 * 64];
  const int tid = threadIdx.x;
  const int w = tid >> 6, lane = tid & 63;
  const int g16 = lane >> 4, l16 = lane & 15;
  const int wr = w >> 1, wc = w & 1;
  const int bm0 = blockIdx.y * 128, bn0 = blockIdx.x * 64;
  const int srow = tid >> 3, scc = tid & 7;

  f32x4 acc[4][2];
#pragma unroll
  for (int i = 0; i < 4; ++i)
#pragma unroll
    for (int j = 0; j < 2; ++j)
      acc[i][j] = (f32x4){0.f, 0.f, 0.f, 0.f};

  for (int k0 = 0; k0 < K; k0 += 64) {
#pragma unroll
    for (int i = 0; i < 4; ++i) {
      int row = i * 32 + srow;
      int sw = scc ^ (row & 7);
      gl_lds16(A + (size_t)(bm0 + row) * K + k0 + sw * 8,
               (void*)(As + (i * 256 + w * 64) * 8));
    }
#pragma unroll
    for (int i = 0; i < 2; ++i) {
      int row = i * 32 + srow;
      int sw = scc ^ (row & 7);
      gl_lds16(W + (size_t)(bn0 + row) * K + k0 + sw * 8,
               (void*)(Bs + (i * 256 + w * 64) * 8));
    }
    __syncthreads();
#pragma unroll
    for (int ks = 0; ks < 2; ++ks) {
      bf16x8 af[4], bfr[2];
#pragma unroll
      for (int mt = 0; mt < 4; ++mt) {
        int row = wr * 64 + mt * 16 + l16;
        af[mt] = *(const bf16x8*)&As[row * 64 + (((ks * 4 + g16) ^ (row & 7)) * 8)];
      }
#pragma unroll
      for (int nt = 0; nt < 2; ++nt) {
        int row = wc * 32 + nt * 16 + l16;
        bfr[nt] = *(const bf16x8*)&Bs[row * 64 + (((ks * 4 + g16) ^ (row & 7)) * 8)];
      }
#pragma unroll
      for (int mt = 0; mt < 4; ++mt)
#pragma unroll
        for (int nt = 0; nt < 2; ++nt)
          acc[mt][nt] = __builtin_amdgcn_mfma_f32_16x16x32_bf16(af[mt], bfr[nt], acc[mt][nt], 0, 0, 0);
    }
    __syncthreads();
  }

#pragma unroll
  for (int nt = 0; nt < 2; ++nt) {
    int col = bn0 + wc * 32 + nt * 16 + l16;
    float bcol = bias[col];
#pragma unroll
    for (int mt = 0; mt < 4; ++mt) {
      int row0 = bm0 + wr * 64 + mt * 16 + g16 * 4;
#pragma unroll
      for (int r = 0; r < 4; ++r)
        C[(size_t)(row0 + r) * N + col] = acc[mt][nt][r] + bcol;
    }
  }
}

// ---------------- flash attention ----------------
// grid (SEQ/128, H); 4 waves/block; wave owns 32 q-rows (two 16-row groups
// sharing the K/V LDS fragments -> DS reads per score halved vs QBLK=16).
// Q pre-scaled by log2(e)/sqrt(dk); swapped QK^T; denominator via ones-MFMA.
__global__ __launch_bounds__(256, 3) void attn_fwd(
    const unsigned short* __restrict__ Qm, const unsigned short* __restrict__ Km,
    const unsigned short* __restrict__ Vtm, unsigned short* __restrict__ Xm) {
  __shared__ __align__(16) unsigned short Ksm[2 * 4096];
  __shared__ __align__(16) unsigned short Vsm[2 * 4096];
  __shared__ __align__(16) unsigned short Psm[8192];
  const int tid = threadIdx.x;
  const int w = tid >> 6, lane = tid & 63;
  const int g = lane >> 4, qi = lane & 15;
  const int hb = blockIdx.y * DKH;
  const int q0 = blockIdx.x * 128 + w * 32;
  const int srow = tid >> 3, scc = tid & 7;
  const float THR = 12.0f;

  // staging source pointers (tile 0), pre-swizzled chunk = scc ^ (row&7)
  const int r0 = srow, r1 = 32 + srow;
  const unsigned short* kp0 = Km + (size_t)r0 * DMODEL + hb + (scc ^ (r0 & 7)) * 8;
  const unsigned short* kp1 = Km + (size_t)r1 * DMODEL + hb + (scc ^ (r1 & 7)) * 8;
  const unsigned short* vp0 = Vtm + (size_t)(hb + r0) * SEQL + (scc ^ (r0 & 7)) * 8;
  const unsigned short* vp1 = Vtm + (size_t)(hb + r1) * SEQL + (scc ^ (r1 & 7)) * 8;
  unsigned short* kd0 = Ksm + (w * 64) * 8;
  unsigned short* kd1 = Ksm + (256 + w * 64) * 8;
  unsigned short* vd0 = Vsm + (w * 64) * 8;
  unsigned short* vd1 = Vsm + (256 + w * 64) * 8;

  // loop-invariant LDS read bases (row = sub*16 + qi => row&7 == qi&7)
  const unsigned short* kb0 = &Ksm[qi * 64 + (((0 + g) ^ (qi & 7)) * 8)];
  const unsigned short* kb1 = &Ksm[qi * 64 + (((4 + g) ^ (qi & 7)) * 8)];
  const unsigned short* vrb0 = &Vsm[qi * 64 + (((0 + g) ^ (qi & 7)) * 8)];
  const unsigned short* vrb1 = &Vsm[qi * 64 + (((4 + g) ^ (qi & 7)) * 8)];

  // P-LDS addresses; wave slice 2048 shorts, q-group h adds 1024 shorts
  const int pwb = w * 2048 + qi * 64 + (g & 1) * 4;
  const int pw0 = pwb + (((0 + (g >> 1)) ^ (qi & 7)) * 8);
  const int pw1 = pwb + (((2 + (g >> 1)) ^ (qi & 7)) * 8);
  const int pw2 = pwb + (((4 + (g >> 1)) ^ (qi & 7)) * 8);
  const int pw3 = pwb + (((6 + (g >> 1)) ^ (qi & 7)) * 8);
  const unsigned short* prb0 = &Psm[w * 2048 + qi * 64 + (((0 + g) ^ (qi & 7)) * 8)];
  const unsigned short* prb1 = &Psm[w * 2048 + qi * 64 + (((4 + g) ^ (qi & 7)) * 8)];

  // ones B-fragment for the denominator MFMA
  union { uint32_t u[4]; bf16x8 v; } onef;
  onef.u[0] = onef.u[1] = onef.u[2] = onef.u[3] = 0x3F803F80u;

  // Q fragments: lane holds Q[q0 + h*16 + qi][k = ks*32 + g*8 + j]
  bf16x8 qf[2][2];
#pragma unroll
  for (int h = 0; h < 2; ++h)
#pragma unroll
    for (int ks = 0; ks < 2; ++ks)
      qf[h][ks] = *(const bf16x8*)&Qm[(size_t)(q0 + h * 16 + qi) * DMODEL + hb + ks * 32 + g * 8];

  f32x4 oacc[2][4];
#pragma unroll
  for (int h = 0; h < 2; ++h)
#pragma unroll
    for (int i = 0; i < 4; ++i) oacc[h][i] = (f32x4){0.f, 0.f, 0.f, 0.f};
  f32x4 lacc[2];
  lacc[0] = lacc[1] = (f32x4){0.f, 0.f, 0.f, 0.f};
  float mrun[2] = {-1e30f, -1e30f};

  // prologue: stage tile 0 into buf 0
  gl_lds16(kp0, kd0); gl_lds16(kp1, kd1);
  gl_lds16(vp0, vd0); gl_lds16(vp1, vd1);
  kp0 += 64 * DMODEL; kp1 += 64 * DMODEL; vp0 += 64; vp1 += 64;
  asm volatile("s_waitcnt vmcnt(0)" ::: "memory");
  __builtin_amdgcn_s_barrier();

#define ATTN_STEP(BUF)                                                         \
  do {                                                                         \
    gl_lds16(kp0, kd0 + ((BUF) ^ 1) * 4096);                                   \
    gl_lds16(kp1, kd1 + ((BUF) ^ 1) * 4096);                                   \
    gl_lds16(vp0, vd0 + ((BUF) ^ 1) * 4096);                                   \
    gl_lds16(vp1, vd1 + ((BUF) ^ 1) * 4096);                                   \
    kp0 += 64 * DMODEL; kp1 += 64 * DMODEL; vp0 += 64; vp1 += 64;              \
    f32x4 sv[2][4];                                                            \
    _Pragma("unroll")                                                          \
    for (int h = 0; h < 2; ++h)                                                \
      _Pragma("unroll")                                                        \
      for (int kvt = 0; kvt < 4; ++kvt) sv[h][kvt] = (f32x4){0.f, 0.f, 0.f, 0.f}; \
    __builtin_amdgcn_s_setprio(1);                                             \
    _Pragma("unroll")                                                          \
    for (int kvt = 0; kvt < 4; ++kvt) {                                        \
      bf16x8 ka0 = *(const bf16x8*)(kb0 + (BUF) * 4096 + kvt * 1024);          \
      bf16x8 ka1 = *(const bf16x8*)(kb1 + (BUF) * 4096 + kvt * 1024);          \
      _Pragma("unroll")                                                        \
      for (int h = 0; h < 2; ++h) {                                            \
        sv[h][kvt] = __builtin_amdgcn_mfma_f32_16x16x32_bf16(ka0, qf[h][0], sv[h][kvt], 0, 0, 0); \
        sv[h][kvt] = __builtin_amdgcn_mfma_f32_16x16x32_bf16(ka1, qf[h][1], sv[h][kvt], 0, 0, 0); \
      }                                                                        \
    }                                                                          \
    __builtin_amdgcn_s_setprio(0);                                             \
    float tmax[2];                                                             \
    _Pragma("unroll")                                                          \
    for (int h = 0; h < 2; ++h) {                                              \
      float tm = sv[h][0][0];                                                  \
      _Pragma("unroll")                                                        \
      for (int kvt = 0; kvt < 4; ++kvt)                                        \
        _Pragma("unroll")                                                      \
        for (int r = 0; r < 4; ++r) tm = fmaxf(tm, sv[h][kvt][r]);             \
      tm = fmaxf(tm, __shfl_xor(tm, 16));                                      \
      tm = fmaxf(tm, __shfl_xor(tm, 32));                                      \
      tmax[h] = tm;                                                            \
    }                                                                          \
    float need = fmaxf(tmax[0] - mrun[0], tmax[1] - mrun[1]);                  \
    if (__any(need > THR)) {                                                   \
      _Pragma("unroll")                                                        \
      for (int h = 0; h < 2; ++h) {                                            \
        float mnew = fmaxf(mrun[h], tmax[h]);                                  \
        float alpha = fast_exp2(mrun[h] - mnew);                               \
        _Pragma("unroll")                                                      \
        for (int r = 0; r < 4; ++r) {                                          \
          float ar = __shfl(alpha, (lane & 48) + g * 4 + r);                   \
          lacc[h][r] *= ar;                                                    \
          _Pragma("unroll")                                                    \
          for (int dg = 0; dg < 4; ++dg) oacc[h][dg][r] *= ar;                 \
        }                                                                      \
        mrun[h] = mnew;                                                        \
      }                                                                        \
    }                                                                          \
    _Pragma("unroll")                                                          \
    for (int h = 0; h < 2; ++h) {                                              \
      float p[16];                                                             \
      _Pragma("unroll")                                                        \
      for (int kvt = 0; kvt < 4; ++kvt)                                        \
        _Pragma("unroll")                                                      \
        for (int r = 0; r < 4; ++r)                                            \
          p[kvt * 4 + r] = fast_exp2(sv[h][kvt][r] - mrun[h]);                 \
      uint2 pk;                                                                \
      pk.x = cvt_pk_bf16(p[0], p[1]);  pk.y = cvt_pk_bf16(p[2], p[3]);         \
      *(uint2*)&Psm[pw0 + h * 1024] = pk;                                      \
      pk.x = cvt_pk_bf16(p[4], p[5]);  pk.y = cvt_pk_bf16(p[6], p[7]);         \
      *(uint2*)&Psm[pw1 + h * 1024] = pk;                                      \
      pk.x = cvt_pk_bf16(p[8], p[9]);  pk.y = cvt_pk_bf16(p[10], p[11]);       \
      *(uint2*)&Psm[pw2 + h * 1024] = pk;                                      \
      pk.x = cvt_pk_bf16(p[12], p[13]); pk.y = cvt_pk_bf16(p[14], p[15]);      \
      *(uint2*)&Psm[pw3 + h * 1024] = pk;                                      \
    }                                                                          \
    bf16x8 pa[2][2];                                                           \
    _Pragma("unroll")                                                          \
    for (int h = 0; h < 2; ++h) {                                              \
      pa[h][0] = *(const bf16x8*)(prb0 + h * 1024);                            \
      pa[h][1] = *(const bf16x8*)(prb1 + h * 1024);                            \
    }                                                                          \
    __builtin_amdgcn_s_setprio(1);                                             \
    _Pragma("unroll")                                                          \
    for (int h = 0; h < 2; ++h) {                                              \
      lacc[h] = __builtin_amdgcn_mfma_f32_16x16x32_bf16(pa[h][0], onef.v, lacc[h], 0, 0, 0); \
      lacc[h] = __builtin_amdgcn_mfma_f32_16x16x32_bf16(pa[h][1], onef.v, lacc[h], 0, 0, 0); \
    }                                                                          \
    _Pragma("unroll")                                                          \
    for (int dg = 0; dg < 4; ++dg) {                                           \
      bf16x8 vb0 = *(const bf16x8*)(vrb0 + (BUF) * 4096 + dg * 1024);          \
      bf16x8 vb1 = *(const bf16x8*)(vrb1 + (BUF) * 4096 + dg * 1024);          \
      _Pragma("unroll")                                                        \
      for (int h = 0; h < 2; ++h) {                                            \
        oacc[h][dg] = __builtin_amdgcn_mfma_f32_16x16x32_bf16(pa[h][0], vb0, oacc[h][dg], 0, 0, 0); \
        oacc[h][dg] = __builtin_amdgcn_mfma_f32_16x16x32_bf16(pa[h][1], vb1, oacc[h][dg], 0, 0, 0); \
      }                                                                        \
    }                                                                          \
    __builtin_amdgcn_s_setprio(0);                                             \
    asm volatile("s_waitcnt vmcnt(0)" ::: "memory");                           \
    __builtin_amdgcn_s_barrier();                                              \
  } while (0)

  for (int tt = 0; tt < SEQL / 128; ++tt) {
    ATTN_STEP(0);
    ATTN_STEP(1);
  }
#undef ATTN_STEP

#pragma unroll
  for (int h = 0; h < 2; ++h)
#pragma unroll
    for (int r = 0; r < 4; ++r) {
      float inv = 1.f / lacc[h][r];
      int row = q0 + h * 16 + g * 4 + r;
#pragma unroll
      for (int dg = 0; dg < 4; ++dg)
        Xm[(size_t)row * DMODEL + hb + dg * 16 + qi] = f2bf(oacc[h][dg][r] * inv);
    }
}

// ---------------- launch ----------------
extern "C" void kernel_launch(void* const* d_in, const int* in_sizes, int n_in,
                              void* d_out, int out_size, void* d_ws, size_t ws_size,
                              hipStream_t stream) {
  const float* query = (const float*)d_in[0];
  const float* key_  = (const float*)d_in[1];
  const float* value = (const float*)d_in[2];
  const float* Wq = (const float*)d_in[3];
  const float* bq = (const float*)d_in[4];
  const float* Wk = (const float*)d_in[5];
  const float* bk = (const float*)d_in[6];
  const float* Wv = (const float*)d_in[7];
  const float* bv = (const float*)d_in[8];
  const float* Wo = (const float*)d_in[9];
  const float* bo = (const float*)d_in[10];

  char* ws = (char*)d_ws;
  const size_t MB = 1024 * 1024;
  unsigned short* qb  = (unsigned short*)(ws + 0 * MB);
  unsigned short* kb  = (unsigned short*)(ws + 8 * MB);
  unsigned short* vb  = (unsigned short*)(ws + 16 * MB);
  unsigned short* wqb = (unsigned short*)(ws + 24 * MB);
  unsigned short* wkb = (unsigned short*)(ws + 26 * MB);
  unsigned short* wvb = (unsigned short*)(ws + 28 * MB);
  unsigned short* wob = (unsigned short*)(ws + 30 * MB);
  unsigned short* Qp  = (unsigned short*)(ws + 32 * MB);
  unsigned short* Kp  = (unsigned short*)(ws + 40 * MB);
  unsigned short* Vtp = (unsigned short*)(ws + 48 * MB);
  unsigned short* Xp  = (unsigned short*)(ws + 56 * MB);

  CvtArgs ca{query, key_, value, Wq, Wk, Wv, Wo, qb, kb, vb, wqb, wkb, wvb, wob};
  cvt_all<<<dim3(2048), dim3(256), 0, stream>>>(ca);

  const float CE = 0.18033688011112042f; // log2(e)/sqrt(64)
  GemmArgs gp;
  gp.d[0] = GemmDesc{qb, wqb, bq, (void*)Qp, 0, CE};   // Q pre-scaled
  gp.d[1] = GemmDesc{kb, wkb, bk, (void*)Kp, 0, 1.0f};
  gp.d[2] = GemmDesc{vb, wvb, bv, (void*)Vtp, 1, 1.0f}; // V transposed [d][s]
  gemm_bt<<<dim3(8, 32, 3), dim3(256), 0, stream>>>(gp);

  attn_fwd<<<dim3(SEQL / 128, HN), dim3(256), 0, stream>>>(Qp, Kp, Vtp, Xp);

  gemm_o<<<dim3(16, 32), dim3(256), 0, stream>>>(Xp, wob, bo, (float*)d_out);
}